// Round 5
// baseline (471.351 us; speedup 1.0000x reference)
//
#include <hip/hip_runtime.h>

// DilConv fused: ReLU -> depthwise 3x3 (dil 2, SAME) + bias
//              -> pointwise 1x1 (C->C) f16 MFMA + bias -> BN (inference)
// N=32, H=W=56, C=256, fp32 in/out.
//
// Round-5: round-4 skeleton (single kernel, ONE barrier, no d_ws) with the
// spill fixed: B-fragment preload split per nt-half (32 VGPRs live instead of
// 64), nt=1 preload overlapped with nt=0 epilogue stores. Peak reg demand
// ~110 < 128-cap of __launch_bounds__(512,4) -> 4 waves/SIMD, no scratch.

typedef _Float16 f16;
typedef _Float16 f16x4 __attribute__((ext_vector_type(4)));
typedef _Float16 f16x8 __attribute__((ext_vector_type(8)));
typedef float    f32x4 __attribute__((ext_vector_type(4)));

constexpr int   N_ = 32, H_ = 56, W_ = 56, C_ = 256;
constexpr float BN_EPS = 1e-3f;

// LDS: d[p][ch] f16, row 512B, 16B slots XOR-swizzled by (p&7); + offC. 33 KB.
struct SM {
    f16   d[64 * 256];   // 32768 B
    float offC[256];     //  1024 B
};

__global__ __launch_bounds__(512, 4)
void dilconv_fused(const float* __restrict__ x,
                   const float* __restrict__ dwk,
                   const float* __restrict__ dwb,
                   const float* __restrict__ pwk,
                   const float* __restrict__ pwb,
                   const float* __restrict__ gamma,
                   const float* __restrict__ beta,
                   const float* __restrict__ mmean,
                   const float* __restrict__ mvar,
                   float* __restrict__ out)
{
    __shared__ SM sm;

    const int tid = threadIdx.x;
    const int l   = tid & 63;
    const int wq  = tid >> 6;                                    // 0..7
    const int bid = (blockIdx.x & 7) * 196 + (blockIdx.x >> 3);  // XCD swizzle (1568=8*196)
    const int n   = bid / 49;
    const int t   = bid % 49;
    const int h0  = (t / 7) * 8;
    const int w0  = (t % 7) * 8;

    // ---- BN fold -> offC ----
    if (tid < 256) {
        const float iv = gamma[tid] * rsqrtf(mvar[tid] + BN_EPS);
        sm.offC[tid] = pwb[tid] * iv + beta[tid] - mmean[tid] * iv;
    }

    // ---- phase 1: ReLU + dilated depthwise + bias -> sm.d (f16, swizzled) ----
    // thread = (out row r = wq, channels c4..c4+3), 8 out cols, row-reuse loads.
    {
        const int r  = wq;
        const int c4 = l << 2;
        const int ph = h0 + r;
        float4 a[8];
        const float4 bias = *reinterpret_cast<const float4*>(dwb + c4);
        #pragma unroll
        for (int ow = 0; ow < 8; ++ow) a[ow] = bias;

        #pragma unroll
        for (int kh = 0; kh < 3; ++kh) {
            const int  ih  = ph + 2 * kh - 2;
            const bool rok = (unsigned)ih < (unsigned)H_;
            const int  ihc = rok ? ih : 0;
            const float* xrow = x + ((size_t)(n * H_ + ihc) * W_) * C_ + c4;
            float4 ld[12];
            #pragma unroll
            for (int ci = 0; ci < 12; ++ci) {
                const int  iw  = w0 + ci - 2;
                const bool ok  = rok && ((unsigned)iw < (unsigned)W_);
                const int  iwc = ok ? iw : 0;
                float4 v = *reinterpret_cast<const float4*>(xrow + (size_t)iwc * C_);
                v.x = ok ? fmaxf(v.x, 0.f) : 0.f;
                v.y = ok ? fmaxf(v.y, 0.f) : 0.f;
                v.z = ok ? fmaxf(v.z, 0.f) : 0.f;
                v.w = ok ? fmaxf(v.w, 0.f) : 0.f;
                ld[ci] = v;
            }
            #pragma unroll
            for (int kw = 0; kw < 3; ++kw) {
                const float4 kv = *reinterpret_cast<const float4*>(dwk + (kh * 3 + kw) * C_ + c4);
                #pragma unroll
                for (int ow = 0; ow < 8; ++ow) {
                    a[ow].x = fmaf(ld[ow + 2 * kw].x, kv.x, a[ow].x);
                    a[ow].y = fmaf(ld[ow + 2 * kw].y, kv.y, a[ow].y);
                    a[ow].z = fmaf(ld[ow + 2 * kw].z, kv.z, a[ow].z);
                    a[ow].w = fmaf(ld[ow + 2 * kw].w, kv.w, a[ow].w);
                }
            }
        }
        #pragma unroll
        for (int ow = 0; ow < 8; ++ow) {
            const int p = r * 8 + ow;
            const f16x4 hv = { (f16)a[ow].x, (f16)a[ow].y, (f16)a[ow].z, (f16)a[ow].w };
            const int slot = c4 >> 3;
            const int idx  = p * 256 + (((slot ^ (p & 7)) << 3) | (c4 & 7));
            *reinterpret_cast<f16x4*>(&sm.d[idx]) = hv;
        }
    }

    // Keep the B-preload out of phase 1's high-pressure live range.
    __builtin_amdgcn_sched_barrier(0);

    const int arow  = l & 15;
    const int koctl = l >> 4;

    // B-frag gather (BN-scale folded, fp32 -> f16 in flight), 32 VGPRs.
    auto load_bw = [&](int nt, f16x8 (&bw)[8]) {
        const int co = wq * 32 + nt * 16 + arow;
        const float iv = gamma[co] * rsqrtf(mvar[co] + BN_EPS);
        #pragma unroll
        for (int ks = 0; ks < 8; ++ks) {
            const int slot = ks * 4 + koctl;
            const float* wp = pwk + (size_t)(slot * 8) * C_ + co;
            f16x8 h;
            #pragma unroll
            for (int j = 0; j < 8; ++j)
                h[j] = (f16)(wp[(size_t)j * C_] * iv);
            bw[ks] = h;
        }
    };

    // Run 8 k-octets of MFMA for one nt-half (A from LDS, B from regs).
    auto run_mfma = [&](const f16x8 (&bw)[8], f32x4 (&acc)[4]) {
        #pragma unroll
        for (int ks = 0; ks < 8; ++ks) {
            const int slot = ks * 4 + koctl;
            #pragma unroll
            for (int mt = 0; mt < 4; ++mt) {
                const int row = mt * 16 + arow;
                const f16x8 af = *reinterpret_cast<const f16x8*>(
                    &sm.d[row * 256 + ((slot ^ (row & 7)) << 3)]);
                acc[mt] = __builtin_amdgcn_mfma_f32_16x16x32_f16(
                    af, bw[ks], acc[mt], 0, 0, 0);
            }
        }
    };

    auto store_half = [&](int nt, const f32x4 (&acc)[4]) {
        const int   co  = wq * 32 + nt * 16 + arow;
        const float off = sm.offC[co];
        #pragma unroll
        for (int mt = 0; mt < 4; ++mt) {
            #pragma unroll
            for (int rg = 0; rg < 4; ++rg) {
                const int p  = mt * 16 + koctl * 4 + rg;   // C/D: row=(l>>4)*4+reg
                const int oh = h0 + (p >> 3);
                const int ow = w0 + (p & 7);
                out[((size_t)((n * H_ + oh) * W_ + ow)) * C_ + co] = acc[mt][rg] + off;
            }
        }
    };

    // nt=0 preload overlaps the barrier wait / other waves' phase 1.
    f16x8 bw0[8];
    load_bw(0, bw0);

    __syncthreads();   // the ONLY barrier

    f32x4 acc0[4];
    #pragma unroll
    for (int i = 0; i < 4; ++i) acc0[i] = (f32x4){0.f, 0.f, 0.f, 0.f};
    run_mfma(bw0, acc0);

    // Issue nt=1 gathers, hide their latency under nt=0 epilogue stores.
    f16x8 bw1[8];
    load_bw(1, bw1);
    store_half(0, acc0);

    f32x4 acc1[4];
    #pragma unroll
    for (int i = 0; i < 4; ++i) acc1[i] = (f32x4){0.f, 0.f, 0.f, 0.f};
    run_mfma(bw1, acc1);
    store_half(1, acc1);
}

extern "C" void kernel_launch(void* const* d_in, const int* in_sizes, int n_in,
                              void* d_out, int out_size, void* d_ws, size_t ws_size,
                              hipStream_t stream) {
    const float* x     = (const float*)d_in[0];
    const float* dwk   = (const float*)d_in[1];
    const float* dwb   = (const float*)d_in[2];
    const float* pwk   = (const float*)d_in[3];
    const float* pwb   = (const float*)d_in[4];
    const float* gam   = (const float*)d_in[5];
    const float* bet   = (const float*)d_in[6];
    const float* mmean = (const float*)d_in[7];
    const float* mvar  = (const float*)d_in[8];
    float* out = (float*)d_out;

    dilconv_fused<<<dim3(N_ * 49), dim3(512), 0, stream>>>(
        x, dwk, dwb, pwk, pwb, gam, bet, mmean, mvar, out);
}

// Round 6
// 439.184 us; speedup vs baseline: 1.0732x; 1.0732x over previous
//
#include <hip/hip_runtime.h>

// DilConv fused: ReLU -> depthwise 3x3 (dil 2, SAME) + bias
//              -> pointwise 1x1 (C->C) f16 MFMA + bias -> BN (inference)
// N=32, H=W=56, C=256, fp32 in/out.
//
// Round-6: round-5 skeleton (single kernel, ONE barrier, no d_ws) with the
// spill actually fixed:
//  - __launch_bounds__(512,3): ~170-reg cap. (512,4)'s 128-cap made the
//    compiler split 64 VGPR + 64 AGPR and spill ~160 dwords/thread
//    (observed: +520 MB WRITE, +350 MB FETCH of scratch traffic).
//  - B-fragment gather moved AFTER the barrier so its 64-dword burst never
//    overlaps phase-1's ~100-reg live range. nt=1 gather still overlaps the
//    nt=0 epilogue stores (low-pressure region).

typedef _Float16 f16;
typedef _Float16 f16x4 __attribute__((ext_vector_type(4)));
typedef _Float16 f16x8 __attribute__((ext_vector_type(8)));
typedef float    f32x4 __attribute__((ext_vector_type(4)));

constexpr int   N_ = 32, H_ = 56, W_ = 56, C_ = 256;
constexpr float BN_EPS = 1e-3f;

// LDS: d[p][ch] f16, row 512B, 16B slots XOR-swizzled by (p&7); + offC. 33 KB.
struct SM {
    f16   d[64 * 256];   // 32768 B
    float offC[256];     //  1024 B
};

__global__ __launch_bounds__(512, 3)
void dilconv_fused(const float* __restrict__ x,
                   const float* __restrict__ dwk,
                   const float* __restrict__ dwb,
                   const float* __restrict__ pwk,
                   const float* __restrict__ pwb,
                   const float* __restrict__ gamma,
                   const float* __restrict__ beta,
                   const float* __restrict__ mmean,
                   const float* __restrict__ mvar,
                   float* __restrict__ out)
{
    __shared__ SM sm;

    const int tid = threadIdx.x;
    const int l   = tid & 63;
    const int wq  = tid >> 6;                                    // 0..7
    const int bid = (blockIdx.x & 7) * 196 + (blockIdx.x >> 3);  // XCD swizzle (1568=8*196)
    const int n   = bid / 49;
    const int t   = bid % 49;
    const int h0  = (t / 7) * 8;
    const int w0  = (t % 7) * 8;

    // ---- BN fold -> offC ----
    if (tid < 256) {
        const float iv = gamma[tid] * rsqrtf(mvar[tid] + BN_EPS);
        sm.offC[tid] = pwb[tid] * iv + beta[tid] - mmean[tid] * iv;
    }

    // ---- phase 1: ReLU + dilated depthwise + bias -> sm.d (f16, swizzled) ----
    // thread = (out row r = wq, channels c4..c4+3), 8 out cols, row-reuse loads.
    {
        const int r  = wq;
        const int c4 = l << 2;
        const int ph = h0 + r;
        float4 a[8];
        const float4 bias = *reinterpret_cast<const float4*>(dwb + c4);
        #pragma unroll
        for (int ow = 0; ow < 8; ++ow) a[ow] = bias;

        #pragma unroll
        for (int kh = 0; kh < 3; ++kh) {
            const int  ih  = ph + 2 * kh - 2;
            const bool rok = (unsigned)ih < (unsigned)H_;
            const int  ihc = rok ? ih : 0;
            const float* xrow = x + ((size_t)(n * H_ + ihc) * W_) * C_ + c4;
            float4 ld[12];
            #pragma unroll
            for (int ci = 0; ci < 12; ++ci) {
                const int  iw  = w0 + ci - 2;
                const bool ok  = rok && ((unsigned)iw < (unsigned)W_);
                const int  iwc = ok ? iw : 0;
                float4 v = *reinterpret_cast<const float4*>(xrow + (size_t)iwc * C_);
                v.x = ok ? fmaxf(v.x, 0.f) : 0.f;
                v.y = ok ? fmaxf(v.y, 0.f) : 0.f;
                v.z = ok ? fmaxf(v.z, 0.f) : 0.f;
                v.w = ok ? fmaxf(v.w, 0.f) : 0.f;
                ld[ci] = v;
            }
            #pragma unroll
            for (int kw = 0; kw < 3; ++kw) {
                const float4 kv = *reinterpret_cast<const float4*>(dwk + (kh * 3 + kw) * C_ + c4);
                #pragma unroll
                for (int ow = 0; ow < 8; ++ow) {
                    a[ow].x = fmaf(ld[ow + 2 * kw].x, kv.x, a[ow].x);
                    a[ow].y = fmaf(ld[ow + 2 * kw].y, kv.y, a[ow].y);
                    a[ow].z = fmaf(ld[ow + 2 * kw].z, kv.z, a[ow].z);
                    a[ow].w = fmaf(ld[ow + 2 * kw].w, kv.w, a[ow].w);
                }
            }
        }
        #pragma unroll
        for (int ow = 0; ow < 8; ++ow) {
            const int p = r * 8 + ow;
            const f16x4 hv = { (f16)a[ow].x, (f16)a[ow].y, (f16)a[ow].z, (f16)a[ow].w };
            const int slot = c4 >> 3;
            const int idx  = p * 256 + (((slot ^ (p & 7)) << 3) | (c4 & 7));
            *reinterpret_cast<f16x4*>(&sm.d[idx]) = hv;
        }
    }

    __builtin_amdgcn_sched_barrier(0);   // phase-1 live range ends here
    __syncthreads();                     // the ONLY barrier
    __builtin_amdgcn_sched_barrier(0);   // keep B-gather out of phase 1

    const int arow  = l & 15;
    const int koctl = l >> 4;

    // B-frag gather (BN-scale folded, fp32 -> f16 in flight), 32 VGPRs packed.
    auto load_bw = [&](int nt, f16x8 (&bw)[8]) {
        const int co = wq * 32 + nt * 16 + arow;
        const float iv = gamma[co] * rsqrtf(mvar[co] + BN_EPS);
        #pragma unroll
        for (int ks = 0; ks < 8; ++ks) {
            const int slot = ks * 4 + koctl;
            const float* wp = pwk + (size_t)(slot * 8) * C_ + co;
            f16x8 h;
            #pragma unroll
            for (int j = 0; j < 8; ++j)
                h[j] = (f16)(wp[(size_t)j * C_] * iv);
            bw[ks] = h;
        }
    };

    // 8 k-octets of MFMA for one nt-half (A from LDS, B from regs).
    auto run_mfma = [&](const f16x8 (&bw)[8], f32x4 (&acc)[4]) {
        #pragma unroll
        for (int ks = 0; ks < 8; ++ks) {
            const int slot = ks * 4 + koctl;
            #pragma unroll
            for (int mt = 0; mt < 4; ++mt) {
                const int row = mt * 16 + arow;
                const f16x8 af = *reinterpret_cast<const f16x8*>(
                    &sm.d[row * 256 + ((slot ^ (row & 7)) << 3)]);
                acc[mt] = __builtin_amdgcn_mfma_f32_16x16x32_f16(
                    af, bw[ks], acc[mt], 0, 0, 0);
            }
        }
    };

    auto store_half = [&](int nt, const f32x4 (&acc)[4]) {
        const int   co  = wq * 32 + nt * 16 + arow;
        const float off = sm.offC[co];
        #pragma unroll
        for (int mt = 0; mt < 4; ++mt) {
            #pragma unroll
            for (int rg = 0; rg < 4; ++rg) {
                const int p  = mt * 16 + koctl * 4 + rg;   // C/D: row=(l>>4)*4+reg
                const int oh = h0 + (p >> 3);
                const int ow = w0 + (p & 7);
                out[((size_t)((n * H_ + oh) * W_ + ow)) * C_ + co] = acc[mt][rg] + off;
            }
        }
    };

    f16x8 bw0[8];
    load_bw(0, bw0);

    f32x4 acc0[4];
    #pragma unroll
    for (int i = 0; i < 4; ++i) acc0[i] = (f32x4){0.f, 0.f, 0.f, 0.f};
    run_mfma(bw0, acc0);

    // Issue nt=1 gathers, hide their latency under nt=0 epilogue stores.
    f16x8 bw1[8];
    load_bw(1, bw1);
    store_half(0, acc0);

    f32x4 acc1[4];
    #pragma unroll
    for (int i = 0; i < 4; ++i) acc1[i] = (f32x4){0.f, 0.f, 0.f, 0.f};
    run_mfma(bw1, acc1);
    store_half(1, acc1);
}

extern "C" void kernel_launch(void* const* d_in, const int* in_sizes, int n_in,
                              void* d_out, int out_size, void* d_ws, size_t ws_size,
                              hipStream_t stream) {
    const float* x     = (const float*)d_in[0];
    const float* dwk   = (const float*)d_in[1];
    const float* dwb   = (const float*)d_in[2];
    const float* pwk   = (const float*)d_in[3];
    const float* pwb   = (const float*)d_in[4];
    const float* gam   = (const float*)d_in[5];
    const float* bet   = (const float*)d_in[6];
    const float* mmean = (const float*)d_in[7];
    const float* mvar  = (const float*)d_in[8];
    float* out = (float*)d_out;

    dilconv_fused<<<dim3(N_ * 49), dim3(512), 0, stream>>>(
        x, dwk, dwb, pwk, pwb, gam, bet, mmean, mvar, out);
}